// Round 3
// baseline (351.298 us; speedup 1.0000x reference)
//
#include <hip/hip_runtime.h>

#define PI_F 3.14159265358979f

__device__ __forceinline__ float2 cadd(float2 a, float2 b){ return make_float2(a.x+b.x, a.y+b.y); }
__device__ __forceinline__ float2 csub(float2 a, float2 b){ return make_float2(a.x-b.x, a.y-b.y); }
__device__ __forceinline__ float2 cmul(float2 a, float2 b){ return make_float2(a.x*b.x - a.y*b.y, a.x*b.y + a.y*b.x); }

// XOR swizzle on complex index for FFT ping-pong buffers (kills stride-4 write conflicts)
#define PH(i) ((i) ^ ((((unsigned)(i))>>5)&7))

// ---------------- kernel A: per-row softmax stats (max, 1/sumexp) ----------------
__global__ __launch_bounds__(256) void ksoft(const float* __restrict__ sel,
                                             float* __restrict__ rowmax,
                                             float* __restrict__ rowinv)
{
    const int row = blockIdx.x;
    const int tid = threadIdx.x;
    const float4* p4 = (const float4*)(sel + (size_t)row * 4096);
    float4 v[4];
    float mx = -3.0e38f;
#pragma unroll
    for (int i = 0; i < 4; ++i) {
        v[i] = p4[tid + (i<<8)];
        mx = fmaxf(mx, fmaxf(fmaxf(v[i].x, v[i].y), fmaxf(v[i].z, v[i].w)));
    }
#pragma unroll
    for (int o = 32; o >= 1; o >>= 1) mx = fmaxf(mx, __shfl_xor(mx, o));
    __shared__ float red[8];
    const int wv = tid >> 6;
    if ((tid & 63) == 0) red[wv] = mx;
    __syncthreads();
    mx = fmaxf(fmaxf(red[0], red[1]), fmaxf(red[2], red[3]));
    float s = 0.0f;
#pragma unroll
    for (int i = 0; i < 4; ++i) {
        s += __expf(v[i].x - mx) + __expf(v[i].y - mx) + __expf(v[i].z - mx) + __expf(v[i].w - mx);
    }
#pragma unroll
    for (int o = 32; o >= 1; o >>= 1) s += __shfl_xor(s, o);
    if ((tid & 63) == 0) red[4 + wv] = s;
    __syncthreads();
    if (tid == 0) {
        rowmax[row] = mx;
        rowinv[row] = 1.0f / (red[4] + red[5] + red[6] + red[7]);
    }
}

// ---------------- kernel B: GEMM (softmax(sel) @ items) + transform ----------------
// M=1024, N=514, K=4096.  BM=64, BN=32, BK=32, 256 threads.
// P layout (floats): L[1024*257] | M[1024*257] | COS[1024*257] | SIN[1024*257]
__global__ __launch_bounds__(256) void kgemm(const float* __restrict__ sel,
                                             const float* __restrict__ items,
                                             const float* __restrict__ rowmax,
                                             const float* __restrict__ rowinv,
                                             float* __restrict__ P)
{
    __shared__ float As[32*68];  // [k][row], padded
    __shared__ float Bs[32*33];  // [k][col], padded
    const int tid = threadIdx.x;
    const int r0 = blockIdx.x * 64;
    const int c0 = blockIdx.y * 32;

    const int arow = tid >> 2;       // 0..63
    const int ak4  = tid & 3;        // 0..3
    const float mx  = rowmax[r0 + arow];
    const float inv = rowinv[r0 + arow];

    const int bc  = tid & 31;
    const int bkr = tid >> 5;        // 0..7
    const int ccol = c0 + bc;
    const bool cvalid = ccol < 514;

    const int rg = tid >> 5;         // 0..7 (row group)
    const int tx = tid & 31;         // col

    float acc[8];
#pragma unroll
    for (int i = 0; i < 8; ++i) acc[i] = 0.0f;

    for (int k0 = 0; k0 < 4096; k0 += 32) {
        __syncthreads();
#pragma unroll
        for (int h = 0; h < 2; ++h) {
            float4 v = *(const float4*)(sel + (size_t)(r0 + arow)*4096 + k0 + h*16 + ak4*4);
            int kb = h*16 + ak4*4;
            As[(kb+0)*68 + arow] = __expf(v.x - mx) * inv;
            As[(kb+1)*68 + arow] = __expf(v.y - mx) * inv;
            As[(kb+2)*68 + arow] = __expf(v.z - mx) * inv;
            As[(kb+3)*68 + arow] = __expf(v.w - mx) * inv;
        }
#pragma unroll
        for (int i = 0; i < 4; ++i) {
            int kk = bkr + (i<<3);
            Bs[kk*33 + bc] = cvalid ? items[(size_t)(k0 + kk)*514 + ccol] : 0.0f;
        }
        __syncthreads();
#pragma unroll
        for (int kk = 0; kk < 32; ++kk) {
            float b = Bs[kk*33 + tx];
            const float4 a0 = *(const float4*)&As[kk*68 + rg*8];
            const float4 a1 = *(const float4*)&As[kk*68 + rg*8 + 4];
            acc[0] = fmaf(a0.x, b, acc[0]);
            acc[1] = fmaf(a0.y, b, acc[1]);
            acc[2] = fmaf(a0.z, b, acc[2]);
            acc[3] = fmaf(a0.w, b, acc[3]);
            acc[4] = fmaf(a1.x, b, acc[4]);
            acc[5] = fmaf(a1.y, b, acc[5]);
            acc[6] = fmaf(a1.z, b, acc[6]);
            acc[7] = fmaf(a1.w, b, acc[7]);
        }
    }

    if (cvalid) {
        float* Lp = P;
        float* Mp = P + 1024*257;
        float* Cp = P + 2*1024*257;
        float* Sp = P + 3*1024*257;
#pragma unroll
        for (int rr = 0; rr < 8; ++rr) {
            int row = r0 + rg*8 + rr;
            float x = acc[rr];
            if (ccol < 257) {
                float m = 0.9999f / (1.0f + __expf(-x));
                int idx = row*257 + ccol;
                Lp[idx] = __log2f(m);
                Mp[idx] = m;
            } else {
                int idx = row*257 + (ccol - 257);
                float e2 = __expf(2.0f*x);
                float th = (e2 - 1.0f) / (e2 + 1.0f);
                float ph = PI_F * th;
                float sn, cs;
                __sincosf(ph, &sn, &cs);
                Cp[idx] = cs;
                Sp[idx] = sn;
            }
        }
    }
}

// ---------------- kernel C: spectral-window + overlap-add via one IFFT per 256-out block ----
// grid = 1024 items * 8 jgroups; 256 threads = 4 waves; each wave does 4 output blocks.
// out block j (256 samples) = first half of irfft512(H), H[c] = G_j[c] + (-1)^c G_{j-1}[c],
// G = 3-tap Hann conv of F,  F_j = p*m*(cos,sin), F_{j-1} = p*(cos,sin), p = m^j = exp2(j*l).
__global__ __launch_bounds__(256) void kres(const float* __restrict__ P, float* __restrict__ out)
{
    const int tid = threadIdx.x;
    const int lane = tid & 63;
    const int wv = tid >> 6;
    const int item = blockIdx.x >> 3;
    const int jg = blockIdx.x & 7;

    __shared__ float2 tw[256];            // e^{+2πi t/256}
    __shared__ float2 zw[256];            // e^{+2πi t/512}
    __shared__ float2 bufA_s[4][256];
    __shared__ float2 bufB_s[4][257];     // also used as V[0..256]
    __shared__ float2 bufH_s[4][257];

    {
        float s, c;
        __sincosf((6.283185307179586f/256.0f) * (float)tid, &s, &c);
        tw[tid] = make_float2(c, s);
        __sincosf((6.283185307179586f/512.0f) * (float)tid, &s, &c);
        zw[tid] = make_float2(c, s);
    }
    __syncthreads();

    float2* bufA = bufA_s[wv];
    float2* bufB = bufB_s[wv];
    float2* bufH = bufH_s[wv];

    const float* Lp = P;
    const float* Mp = P + 1024*257;
    const float* Cp = P + 2*1024*257;
    const float* Sp = P + 3*1024*257;
    const int pb = item * 257;

    float l[4], mg[4], cf[4], sf[4];
#pragma unroll
    for (int r = 0; r < 4; ++r) {
        int c = lane + (r<<6);
        l[r]  = Lp[pb + c];
        mg[r] = Mp[pb + c];
        cf[r] = Cp[pb + c];
        sf[r] = Sp[pb + c];
    }
    const float l6 = Lp[pb + 256];
    const float m6 = Mp[pb + 256];
    const float c6 = Cp[pb + 256];

    float2* outbase = (float2*)out + (size_t)item * 16384;

    for (int t = 0; t < 4; ++t) {
        const int j = jg*16 + wv + (t<<2);
        const float gf = (j > 0) ? 1.0f : 0.0f;
        const float fj = (float)j;

        // ---- build S (regs) and V (LDS): S = p*(m + (-1)^c*gf)*(cf,sf), V = p*(m - (-1)^c*gf)*(cf,sf)
        float2 S[4];
#pragma unroll
        for (int r = 0; r < 4; ++r) {
            int c = lane + (r<<6);
            float p = exp2f(fj * l[r]);
            float g = (c & 1) ? -gf : gf;
            float as = p * (mg[r] + g);
            float bs = p * (mg[r] - g);
            float2 Sv = make_float2(as * cf[r], as * sf[r]);
            float2 Vv = make_float2(bs * cf[r], bs * sf[r]);
            if (c == 0) { Sv.y = 0.0f; Vv.y = 0.0f; }   // numpy irfft drops imag of DC
            S[r] = Sv;
            bufB[c] = Vv;
        }
        float p6 = exp2f(fj * l6);
        float S6 = p6 * (m6 + gf) * c6;                  // bin 256 real (imag dropped)
        float V6 = p6 * (m6 - gf) * c6;
        if (lane == 0) bufB[256] = make_float2(V6, 0.0f);
        __syncthreads();

        // ---- H[c] = 0.5*S[c] - 0.25*(V[c-1] + V[c+1]); edges use hermitian V[-1]=conj V[1]
#pragma unroll
        for (int r = 0; r < 4; ++r) {
            int c = lane + (r<<6);
            float2 Vm;
            if (c == 0) { float2 v1 = bufB[1]; Vm = make_float2(v1.x, -v1.y); }
            else Vm = bufB[c-1];
            float2 Vp = bufB[c+1];
            bufH[c] = make_float2(0.5f*S[r].x - 0.25f*(Vm.x + Vp.x),
                                  0.5f*S[r].y - 0.25f*(Vm.y + Vp.y));
        }
        if (lane == 0) {
            float2 v255 = bufB[255];
            bufH[256] = make_float2(0.5f*S6 - 0.5f*v255.x, 0.0f);
        }
        __syncthreads();

        // ---- half-size packing: Z[k] = (1/512)[H[k](1+i w) + conj(H[256-k])(1-i w)], w=e^{2πik/512}
#pragma unroll
        for (int r = 0; r < 4; ++r) {
            int k = lane + (r<<6);
            float2 Hk = bufH[k];
            float2 Hm = bufH[256-k];
            float2 w = zw[k];
            float Ar = Hk.x + Hm.x, Ai = Hk.y - Hm.y;
            float Br = Hk.x - Hm.x, Bi = Hk.y + Hm.y;
            float iwr = -w.y*Br - w.x*Bi;
            float iwi =  w.x*Br - w.y*Bi;
            bufA[PH(k)] = make_float2((Ar + iwr)*(1.0f/512.0f), (Ai + iwi)*(1.0f/512.0f));
        }
        __syncthreads();

        // ---- 256-pt complex inverse FFT: 4 radix-4 Stockham stages (sign +)
        float2* src = bufA;
        float2* dst = bufB;
#pragma unroll
        for (int st = 0; st < 4; ++st) {
            const int sh = st << 1;          // 0,2,4,6
            const int s = 1 << sh;           // 1,4,16,64
            const int p = lane >> sh;
            const int q = lane & (s - 1);
            float2 A = src[PH(lane)];
            float2 B = src[PH(lane + 64)];
            float2 C = src[PH(lane + 128)];
            float2 D = src[PH(lane + 192)];
            float2 apc = cadd(A, C), amc = csub(A, C);
            float2 bpd = cadd(B, D);
            float2 jb = make_float2(D.y - B.y, B.x - D.x);   // +i*(B-D)
            int tb = p * s;                                   // twiddle base (256/n == s)
            float2 w1 = tw[tb], w2 = tw[2*tb], w3 = tw[3*tb];
            int ob = q + 4*s*p;
            dst[PH(ob)]       = cadd(apc, bpd);
            dst[PH(ob + s)]   = cmul(w1, cadd(amc, jb));
            dst[PH(ob + 2*s)] = cmul(w2, csub(apc, bpd));
            dst[PH(ob + 3*s)] = cmul(w3, csub(amc, jb));
            __syncthreads();
            float2* tmp = src; src = dst; dst = tmp;
        }

        // ---- y[n] = x[2n] + i x[2n+1]; need n in [0,128) -> 256 output samples, coalesced float2
        float2 y0 = src[PH(lane)];
        float2 y1 = src[PH(lane + 64)];
        float2* o2 = outbase + (j << 7);
        o2[lane] = y0;
        o2[lane + 64] = y1;
        __syncthreads();
    }
}

extern "C" void kernel_launch(void* const* d_in, const int* in_sizes, int n_in,
                              void* d_out, int out_size, void* d_ws, size_t ws_size,
                              hipStream_t stream)
{
    const float* sel   = (const float*)d_in[0];   // (8,32,4,4096) f32 -> [1024][4096]
    const float* items = (const float*)d_in[1];   // (4096,514) f32
    float* out = (float*)d_out;                   // [1024][32768] f32
    float* ws  = (float*)d_ws;

    float* rowmax = ws;            // 1024
    float* rowinv = ws + 1024;     // 1024
    float* P      = ws + 2048;     // 4 * 1024*257 floats (~4.2 MB total)

    ksoft<<<1024, 256, 0, stream>>>(sel, rowmax, rowinv);
    dim3 g2(16, 17);
    kgemm<<<g2, 256, 0, stream>>>(sel, items, rowmax, rowinv, P);
    kres<<<8192, 256, 0, stream>>>(P, out);
}

// Round 4
// 177.559 us; speedup vs baseline: 1.9785x; 1.9785x over previous
//
#include <hip/hip_runtime.h>

#define PI_F 3.14159265358979f
#define NPAD 576
#define KSPLIT 8

__device__ __forceinline__ float2 cadd(float2 a, float2 b){ return make_float2(a.x+b.x, a.y+b.y); }
__device__ __forceinline__ float2 csub(float2 a, float2 b){ return make_float2(a.x-b.x, a.y-b.y); }
__device__ __forceinline__ float2 cmul(float2 a, float2 b){ return make_float2(a.x*b.x - a.y*b.y, a.x*b.y + a.y*b.x); }

// XOR swizzle on complex index for FFT ping-pong buffers (kills stride-4 write conflicts)
#define PH(i) ((i) ^ ((((unsigned)(i))>>5)&7))

// ---------------- kernel A: softmax -> W (normalized weights, f32) ----------------
__global__ __launch_bounds__(256) void ksoftw(const float* __restrict__ sel,
                                              float* __restrict__ Wout)
{
    const int row = blockIdx.x;
    const int tid = threadIdx.x;
    const float4* p4 = (const float4*)(sel + (size_t)row * 4096);
    float4 v[4];
    float mx = -3.0e38f;
#pragma unroll
    for (int i = 0; i < 4; ++i) {
        v[i] = p4[tid + (i<<8)];
        mx = fmaxf(mx, fmaxf(fmaxf(v[i].x, v[i].y), fmaxf(v[i].z, v[i].w)));
    }
#pragma unroll
    for (int o = 32; o >= 1; o >>= 1) mx = fmaxf(mx, __shfl_xor(mx, o));
    __shared__ float red[8];
    const int wv = tid >> 6;
    if ((tid & 63) == 0) red[wv] = mx;
    __syncthreads();
    mx = fmaxf(fmaxf(red[0], red[1]), fmaxf(red[2], red[3]));
    float s = 0.0f;
#pragma unroll
    for (int i = 0; i < 4; ++i) {
        s += __expf(v[i].x - mx) + __expf(v[i].y - mx) + __expf(v[i].z - mx) + __expf(v[i].w - mx);
    }
#pragma unroll
    for (int o = 32; o >= 1; o >>= 1) s += __shfl_xor(s, o);
    if ((tid & 63) == 0) red[4 + wv] = s;
    __syncthreads();
    const float inv = 1.0f / (red[4] + red[5] + red[6] + red[7]);
    float4* w4 = (float4*)(Wout + (size_t)row * 4096);
#pragma unroll
    for (int i = 0; i < 4; ++i) {
        float4 e;
        e.x = __expf(v[i].x - mx) * inv;
        e.y = __expf(v[i].y - mx) * inv;
        e.z = __expf(v[i].z - mx) * inv;
        e.w = __expf(v[i].w - mx) * inv;
        w4[tid + (i<<8)] = e;
    }
}

// ---------------- kernel B: split-K GEMM  Cpart[ks] = W[:, ks] @ items[ks, :] ----------------
// M=1024 N=514(->576) K=4096/KSPLIT per block-z. BM=64 BN=64 BK=16, 256 thr, 4x4/thread.
__global__ __launch_bounds__(256, 2) void kgemm2(const float* __restrict__ W,
                                                 const float* __restrict__ items,
                                                 float* __restrict__ Cpart)
{
    __shared__ float As[16][68];   // [k][m]
    __shared__ float Bs[16][72];   // [k][n]
    const int tid = threadIdx.x;
    const int r0 = blockIdx.x * 64;
    const int c0 = blockIdx.y * 64;
    const int k0 = blockIdx.z * (4096 / KSPLIT);

    const int ty = tid >> 4;              // 0..15 (row group)
    const int tx = tid & 15;              // 0..15 (col group)
    const int am = tid >> 2;              // 0..63  A staging row (m)
    const int ak = (tid & 3) << 2;        // 0,4,8,12  A staging k
    const int brow = tid >> 4;            // 0..15  B staging k
    const int bc4 = (tid & 15) << 2;      // 0..60  B staging col
    const int bcol = c0 + bc4;

    const float* wp = W + (size_t)(r0 + am) * 4096 + k0 + ak;

    float acc[4][4] = {{0.f}};

    for (int kt = 0; kt < (4096 / KSPLIT) / 16; ++kt) {
        const int kb = kt << 4;
        const float4 a = *(const float4*)(wp + kb);
        const float* ip = items + (size_t)(k0 + kb + brow) * 514 + bcol;
        float2 b01 = (bcol     < 514) ? *(const float2*)(ip)     : make_float2(0.f, 0.f);
        float2 b23 = (bcol + 2 < 514) ? *(const float2*)(ip + 2) : make_float2(0.f, 0.f);
        __syncthreads();
        As[ak + 0][am] = a.x;
        As[ak + 1][am] = a.y;
        As[ak + 2][am] = a.z;
        As[ak + 3][am] = a.w;
        *(float4*)&Bs[brow][bc4] = make_float4(b01.x, b01.y, b23.x, b23.y);
        __syncthreads();
#pragma unroll
        for (int kk = 0; kk < 16; ++kk) {
            const float4 av = *(const float4*)&As[kk][ty << 2];
            const float4 bv = *(const float4*)&Bs[kk][tx << 2];
            acc[0][0] = fmaf(av.x, bv.x, acc[0][0]);
            acc[0][1] = fmaf(av.x, bv.y, acc[0][1]);
            acc[0][2] = fmaf(av.x, bv.z, acc[0][2]);
            acc[0][3] = fmaf(av.x, bv.w, acc[0][3]);
            acc[1][0] = fmaf(av.y, bv.x, acc[1][0]);
            acc[1][1] = fmaf(av.y, bv.y, acc[1][1]);
            acc[1][2] = fmaf(av.y, bv.z, acc[1][2]);
            acc[1][3] = fmaf(av.y, bv.w, acc[1][3]);
            acc[2][0] = fmaf(av.z, bv.x, acc[2][0]);
            acc[2][1] = fmaf(av.z, bv.y, acc[2][1]);
            acc[2][2] = fmaf(av.z, bv.z, acc[2][2]);
            acc[2][3] = fmaf(av.z, bv.w, acc[2][3]);
            acc[3][0] = fmaf(av.w, bv.x, acc[3][0]);
            acc[3][1] = fmaf(av.w, bv.y, acc[3][1]);
            acc[3][2] = fmaf(av.w, bv.z, acc[3][2]);
            acc[3][3] = fmaf(av.w, bv.w, acc[3][3]);
        }
    }

    float* cp = Cpart + (size_t)blockIdx.z * (1024 * NPAD)
                      + (size_t)(r0 + (ty << 2)) * NPAD + c0 + (tx << 2);
#pragma unroll
    for (int i = 0; i < 4; ++i) {
        *(float4*)(cp + (size_t)i * NPAD) = make_float4(acc[i][0], acc[i][1], acc[i][2], acc[i][3]);
    }
}

// ---------------- kernel B2: reduce split-K + transform -> P planes ----------------
// P layout (floats): L[1024*257] | M[1024*257] | COS[1024*257] | SIN[1024*257]
__global__ __launch_bounds__(256) void ktrans(const float* __restrict__ Cpart,
                                              float* __restrict__ P)
{
    const int m = blockIdx.x;
    float* Lp = P;
    float* Mp = P + 1024*257;
    float* Cp = P + 2*1024*257;
    float* Sp = P + 3*1024*257;
    for (int c = threadIdx.x; c < 514; c += 256) {
        const float* cp = Cpart + (size_t)m * NPAD + c;
        float x = 0.f;
#pragma unroll
        for (int ks = 0; ks < KSPLIT; ++ks) x += cp[(size_t)ks * (1024 * NPAD)];
        if (c < 257) {
            float mm = 0.9999f / (1.0f + __expf(-x));
            int idx = m*257 + c;
            Lp[idx] = __log2f(mm);
            Mp[idx] = mm;
        } else {
            int idx = m*257 + (c - 257);
            float e2 = __expf(2.0f*x);
            float th = (e2 - 1.0f) / (e2 + 1.0f);
            float ph = PI_F * th;
            float sn, cs;
            __sincosf(ph, &sn, &cs);
            Cp[idx] = cs;
            Sp[idx] = sn;
        }
    }
}

// ---------------- kernel C: spectral-window + overlap-add via one IFFT per 256-out block ----
__global__ __launch_bounds__(256) void kres(const float* __restrict__ P, float* __restrict__ out)
{
    const int tid = threadIdx.x;
    const int lane = tid & 63;
    const int wv = tid >> 6;
    const int item = blockIdx.x >> 3;
    const int jg = blockIdx.x & 7;

    __shared__ float2 tw[256];            // e^{+2πi t/256}
    __shared__ float2 zw[256];            // e^{+2πi t/512}
    __shared__ float2 bufA_s[4][256];
    __shared__ float2 bufB_s[4][257];     // also used as V[0..256]
    __shared__ float2 bufH_s[4][257];

    {
        float s, c;
        __sincosf((6.283185307179586f/256.0f) * (float)tid, &s, &c);
        tw[tid] = make_float2(c, s);
        __sincosf((6.283185307179586f/512.0f) * (float)tid, &s, &c);
        zw[tid] = make_float2(c, s);
    }
    __syncthreads();

    float2* bufA = bufA_s[wv];
    float2* bufB = bufB_s[wv];
    float2* bufH = bufH_s[wv];

    const float* Lp = P;
    const float* Mp = P + 1024*257;
    const float* Cp = P + 2*1024*257;
    const float* Sp = P + 3*1024*257;
    const int pb = item * 257;

    float l[4], mg[4], cf[4], sf[4];
#pragma unroll
    for (int r = 0; r < 4; ++r) {
        int c = lane + (r<<6);
        l[r]  = Lp[pb + c];
        mg[r] = Mp[pb + c];
        cf[r] = Cp[pb + c];
        sf[r] = Sp[pb + c];
    }
    const float l6 = Lp[pb + 256];
    const float m6 = Mp[pb + 256];
    const float c6 = Cp[pb + 256];

    float2* outbase = (float2*)out + (size_t)item * 16384;

    for (int t = 0; t < 4; ++t) {
        const int j = jg*16 + wv + (t<<2);
        const float gf = (j > 0) ? 1.0f : 0.0f;
        const float fj = (float)j;

        // ---- build S (regs) and V (LDS): S = p*(m + (-1)^c*gf)*(cf,sf), V = p*(m - (-1)^c*gf)*(cf,sf)
        float2 S[4];
#pragma unroll
        for (int r = 0; r < 4; ++r) {
            int c = lane + (r<<6);
            float p = exp2f(fj * l[r]);
            float g = (c & 1) ? -gf : gf;
            float as = p * (mg[r] + g);
            float bs = p * (mg[r] - g);
            float2 Sv = make_float2(as * cf[r], as * sf[r]);
            float2 Vv = make_float2(bs * cf[r], bs * sf[r]);
            if (c == 0) { Sv.y = 0.0f; Vv.y = 0.0f; }   // numpy irfft drops imag of DC
            S[r] = Sv;
            bufB[c] = Vv;
        }
        float p6 = exp2f(fj * l6);
        float S6 = p6 * (m6 + gf) * c6;                  // bin 256 real (imag dropped)
        float V6 = p6 * (m6 - gf) * c6;
        if (lane == 0) bufB[256] = make_float2(V6, 0.0f);
        __syncthreads();

        // ---- H[c] = 0.5*S[c] - 0.25*(V[c-1] + V[c+1]); edges use hermitian V[-1]=conj V[1]
#pragma unroll
        for (int r = 0; r < 4; ++r) {
            int c = lane + (r<<6);
            float2 Vm;
            if (c == 0) { float2 v1 = bufB[1]; Vm = make_float2(v1.x, -v1.y); }
            else Vm = bufB[c-1];
            float2 Vp = bufB[c+1];
            bufH[c] = make_float2(0.5f*S[r].x - 0.25f*(Vm.x + Vp.x),
                                  0.5f*S[r].y - 0.25f*(Vm.y + Vp.y));
        }
        if (lane == 0) {
            float2 v255 = bufB[255];
            bufH[256] = make_float2(0.5f*S6 - 0.5f*v255.x, 0.0f);
        }
        __syncthreads();

        // ---- half-size packing: Z[k] = (1/512)[H[k](1+i w) + conj(H[256-k])(1-i w)], w=e^{2πik/512}
#pragma unroll
        for (int r = 0; r < 4; ++r) {
            int k = lane + (r<<6);
            float2 Hk = bufH[k];
            float2 Hm = bufH[256-k];
            float2 w = zw[k];
            float Ar = Hk.x + Hm.x, Ai = Hk.y - Hm.y;
            float Br = Hk.x - Hm.x, Bi = Hk.y + Hm.y;
            float iwr = -w.y*Br - w.x*Bi;
            float iwi =  w.x*Br - w.y*Bi;
            bufA[PH(k)] = make_float2((Ar + iwr)*(1.0f/512.0f), (Ai + iwi)*(1.0f/512.0f));
        }
        __syncthreads();

        // ---- 256-pt complex inverse FFT: 4 radix-4 Stockham stages (sign +)
        float2* src = bufA;
        float2* dst = bufB;
#pragma unroll
        for (int st = 0; st < 4; ++st) {
            const int sh = st << 1;          // 0,2,4,6
            const int s = 1 << sh;           // 1,4,16,64
            const int p = lane >> sh;
            const int q = lane & (s - 1);
            float2 A = src[PH(lane)];
            float2 B = src[PH(lane + 64)];
            float2 C = src[PH(lane + 128)];
            float2 D = src[PH(lane + 192)];
            float2 apc = cadd(A, C), amc = csub(A, C);
            float2 bpd = cadd(B, D);
            float2 jb = make_float2(D.y - B.y, B.x - D.x);   // +i*(B-D)
            int tb = p * s;                                   // twiddle base (256/n == s)
            float2 w1 = tw[tb], w2 = tw[2*tb], w3 = tw[3*tb];
            int ob = q + 4*s*p;
            dst[PH(ob)]       = cadd(apc, bpd);
            dst[PH(ob + s)]   = cmul(w1, cadd(amc, jb));
            dst[PH(ob + 2*s)] = cmul(w2, csub(apc, bpd));
            dst[PH(ob + 3*s)] = cmul(w3, csub(amc, jb));
            __syncthreads();
            float2* tmp = src; src = dst; dst = tmp;
        }

        // ---- y[n] = x[2n] + i x[2n+1]; 256 output samples, coalesced float2
        float2 y0 = src[PH(lane)];
        float2 y1 = src[PH(lane + 64)];
        float2* o2 = outbase + (j << 7);
        o2[lane] = y0;
        o2[lane + 64] = y1;
        __syncthreads();
    }
}

extern "C" void kernel_launch(void* const* d_in, const int* in_sizes, int n_in,
                              void* d_out, int out_size, void* d_ws, size_t ws_size,
                              hipStream_t stream)
{
    const float* sel   = (const float*)d_in[0];   // (8,32,4,4096) f32 -> [1024][4096]
    const float* items = (const float*)d_in[1];   // (4096,514) f32
    float* out = (float*)d_out;                   // [1024][32768] f32 (33.55M floats)
    float* ws  = (float*)d_ws;

    // Scratch carved from d_out (dead by the time kres rewrites all of it):
    float* W     = out;                  // 1024*4096            = 4,194,304 floats
    float* Cpart = out + 4194304;        // KSPLIT*1024*NPAD     = 4,718,592 floats
    float* P     = ws;                   // 4*1024*257           = 1,052,672 floats (in ws)

    ksoftw<<<1024, 256, 0, stream>>>(sel, W);
    dim3 g2(16, 9, KSPLIT);
    kgemm2<<<g2, 256, 0, stream>>>(W, items, Cpart);
    ktrans<<<1024, 256, 0, stream>>>(Cpart, P);
    kres<<<8192, 256, 0, stream>>>(P, out);
}

// Round 5
// 164.260 us; speedup vs baseline: 2.1387x; 1.0810x over previous
//
#include <hip/hip_runtime.h>

#define PI_F 3.14159265358979f
#define NPAD 576
#define KSPLIT 8

__device__ __forceinline__ float2 cadd(float2 a, float2 b){ return make_float2(a.x+b.x, a.y+b.y); }
__device__ __forceinline__ float2 csub(float2 a, float2 b){ return make_float2(a.x-b.x, a.y-b.y); }
__device__ __forceinline__ float2 cmul(float2 a, float2 b){ return make_float2(a.x*b.x - a.y*b.y, a.x*b.y + a.y*b.x); }

// XOR swizzle on complex index for FFT ping-pong buffers (kills stride-4 write conflicts)
#define PH(i) ((i) ^ ((((unsigned)(i))>>5)&7))

// wave-local "barrier": buffers are wave-private, DS ops retire in-order per wave,
// so a lgkmcnt(0) drain + compiler memory fence replaces __syncthreads.
__device__ __forceinline__ void lgkm_sync() {
    asm volatile("s_waitcnt lgkmcnt(0)" ::: "memory");
    __builtin_amdgcn_sched_barrier(0);
}

// ---------------- kernel A: softmax -> W (normalized weights, f32) ----------------
__global__ __launch_bounds__(256) void ksoftw(const float* __restrict__ sel,
                                              float* __restrict__ Wout)
{
    const int row = blockIdx.x;
    const int tid = threadIdx.x;
    const float4* p4 = (const float4*)(sel + (size_t)row * 4096);
    float4 v[4];
    float mx = -3.0e38f;
#pragma unroll
    for (int i = 0; i < 4; ++i) {
        v[i] = p4[tid + (i<<8)];
        mx = fmaxf(mx, fmaxf(fmaxf(v[i].x, v[i].y), fmaxf(v[i].z, v[i].w)));
    }
#pragma unroll
    for (int o = 32; o >= 1; o >>= 1) mx = fmaxf(mx, __shfl_xor(mx, o));
    __shared__ float red[8];
    const int wv = tid >> 6;
    if ((tid & 63) == 0) red[wv] = mx;
    __syncthreads();
    mx = fmaxf(fmaxf(red[0], red[1]), fmaxf(red[2], red[3]));
    float s = 0.0f;
#pragma unroll
    for (int i = 0; i < 4; ++i) {
        s += __expf(v[i].x - mx) + __expf(v[i].y - mx) + __expf(v[i].z - mx) + __expf(v[i].w - mx);
    }
#pragma unroll
    for (int o = 32; o >= 1; o >>= 1) s += __shfl_xor(s, o);
    if ((tid & 63) == 0) red[4 + wv] = s;
    __syncthreads();
    const float inv = 1.0f / (red[4] + red[5] + red[6] + red[7]);
    float4* w4 = (float4*)(Wout + (size_t)row * 4096);
#pragma unroll
    for (int i = 0; i < 4; ++i) {
        float4 e;
        e.x = __expf(v[i].x - mx) * inv;
        e.y = __expf(v[i].y - mx) * inv;
        e.z = __expf(v[i].z - mx) * inv;
        e.w = __expf(v[i].w - mx) * inv;
        w4[tid + (i<<8)] = e;
    }
}

// ---------------- kernel B: split-K GEMM  Cpart[ks] = W[:, ks] @ items[ks, :] ----------------
// M=1024 N=514(->576) K=4096/KSPLIT per block-z. BM=64 BN=64 BK=16, 256 thr, 4x4/thread.
__global__ __launch_bounds__(256, 2) void kgemm2(const float* __restrict__ W,
                                                 const float* __restrict__ items,
                                                 float* __restrict__ Cpart)
{
    __shared__ float As[16][68];   // [k][m]
    __shared__ float Bs[16][72];   // [k][n]
    const int tid = threadIdx.x;
    const int r0 = blockIdx.x * 64;
    const int c0 = blockIdx.y * 64;
    const int k0 = blockIdx.z * (4096 / KSPLIT);

    const int ty = tid >> 4;              // 0..15 (row group)
    const int tx = tid & 15;              // 0..15 (col group)
    const int am = tid >> 2;              // 0..63  A staging row (m)
    const int ak = (tid & 3) << 2;        // 0,4,8,12  A staging k
    const int brow = tid >> 4;            // 0..15  B staging k
    const int bc4 = (tid & 15) << 2;      // 0..60  B staging col
    const int bcol = c0 + bc4;

    const float* wp = W + (size_t)(r0 + am) * 4096 + k0 + ak;

    float acc[4][4] = {{0.f}};

    for (int kt = 0; kt < (4096 / KSPLIT) / 16; ++kt) {
        const int kb = kt << 4;
        const float4 a = *(const float4*)(wp + kb);
        const float* ip = items + (size_t)(k0 + kb + brow) * 514 + bcol;
        float2 b01 = (bcol     < 514) ? *(const float2*)(ip)     : make_float2(0.f, 0.f);
        float2 b23 = (bcol + 2 < 514) ? *(const float2*)(ip + 2) : make_float2(0.f, 0.f);
        __syncthreads();
        As[ak + 0][am] = a.x;
        As[ak + 1][am] = a.y;
        As[ak + 2][am] = a.z;
        As[ak + 3][am] = a.w;
        *(float4*)&Bs[brow][bc4] = make_float4(b01.x, b01.y, b23.x, b23.y);
        __syncthreads();
#pragma unroll
        for (int kk = 0; kk < 16; ++kk) {
            const float4 av = *(const float4*)&As[kk][ty << 2];
            const float4 bv = *(const float4*)&Bs[kk][tx << 2];
            acc[0][0] = fmaf(av.x, bv.x, acc[0][0]);
            acc[0][1] = fmaf(av.x, bv.y, acc[0][1]);
            acc[0][2] = fmaf(av.x, bv.z, acc[0][2]);
            acc[0][3] = fmaf(av.x, bv.w, acc[0][3]);
            acc[1][0] = fmaf(av.y, bv.x, acc[1][0]);
            acc[1][1] = fmaf(av.y, bv.y, acc[1][1]);
            acc[1][2] = fmaf(av.y, bv.z, acc[1][2]);
            acc[1][3] = fmaf(av.y, bv.w, acc[1][3]);
            acc[2][0] = fmaf(av.z, bv.x, acc[2][0]);
            acc[2][1] = fmaf(av.z, bv.y, acc[2][1]);
            acc[2][2] = fmaf(av.z, bv.z, acc[2][2]);
            acc[2][3] = fmaf(av.z, bv.w, acc[2][3]);
            acc[3][0] = fmaf(av.w, bv.x, acc[3][0]);
            acc[3][1] = fmaf(av.w, bv.y, acc[3][1]);
            acc[3][2] = fmaf(av.w, bv.z, acc[3][2]);
            acc[3][3] = fmaf(av.w, bv.w, acc[3][3]);
        }
    }

    float* cp = Cpart + (size_t)blockIdx.z * (1024 * NPAD)
                      + (size_t)(r0 + (ty << 2)) * NPAD + c0 + (tx << 2);
#pragma unroll
    for (int i = 0; i < 4; ++i) {
        *(float4*)(cp + (size_t)i * NPAD) = make_float4(acc[i][0], acc[i][1], acc[i][2], acc[i][3]);
    }
}

// ---------------- kernel B2: reduce split-K + transform -> P planes ----------------
// P layout (floats): L[1024*257] | M[1024*257] | COS[1024*257] | SIN[1024*257]
__global__ __launch_bounds__(256) void ktrans(const float* __restrict__ Cpart,
                                              float* __restrict__ P)
{
    const int m = blockIdx.x;
    float* Lp = P;
    float* Mp = P + 1024*257;
    float* Cp = P + 2*1024*257;
    float* Sp = P + 3*1024*257;
    for (int c = threadIdx.x; c < 514; c += 256) {
        const float* cp = Cpart + (size_t)m * NPAD + c;
        float x = 0.f;
#pragma unroll
        for (int ks = 0; ks < KSPLIT; ++ks) x += cp[(size_t)ks * (1024 * NPAD)];
        if (c < 257) {
            float mm = 0.9999f / (1.0f + __expf(-x));
            int idx = m*257 + c;
            Lp[idx] = __log2f(mm);
            Mp[idx] = mm;
        } else {
            int idx = m*257 + (c - 257);
            float e2 = __expf(2.0f*x);
            float th = (e2 - 1.0f) / (e2 + 1.0f);
            float ph = PI_F * th;
            float sn, cs;
            __sincosf(ph, &sn, &cs);
            Cp[idx] = cs;
            Sp[idx] = sn;
        }
    }
}

// ---------------- kernel C: spectral-window + overlap-add via one IFFT per 256-out block ----
// grid = 1024 items * 8 jgroups; 256 threads = 4 independent waves; each wave does 4 blocks.
// Wave-private LDS buffers + wave-local sync only (no block barriers in the loop).
// Buffers: bufB holds V then Z/ping-pong; bufA holds H then ping-pong. Stage 3 fused to regs.
__global__ __launch_bounds__(256) void kres(const float* __restrict__ P, float* __restrict__ out)
{
    const int tid = threadIdx.x;
    const int lane = tid & 63;
    const int wv = tid >> 6;
    const int item = blockIdx.x >> 3;
    const int jg = blockIdx.x & 7;

    __shared__ float2 tw[256];            // e^{+2πi t/256}
    __shared__ float2 bufA_s[4][257];
    __shared__ float2 bufB_s[4][257];

    {
        float s, c;
        __sincosf((6.283185307179586f/256.0f) * (float)tid, &s, &c);
        tw[tid] = make_float2(c, s);
    }
    __syncthreads();                      // the only block barrier (tw init)

    float2* bufA = bufA_s[wv];
    float2* bufB = bufB_s[wv];

    // zw twiddles e^{+2πi k/512}, k = lane + 64r — loop-invariant, keep in regs
    float2 zwr[4];
#pragma unroll
    for (int r = 0; r < 4; ++r) {
        float s, c;
        __sincosf((6.283185307179586f/512.0f) * (float)(lane + (r<<6)), &s, &c);
        zwr[r] = make_float2(c, s);
    }

    const float* Lp = P;
    const float* Mp = P + 1024*257;
    const float* Cp = P + 2*1024*257;
    const float* Sp = P + 3*1024*257;
    const int pb = item * 257;

    float l[4], mg[4], cf[4], sf[4];
#pragma unroll
    for (int r = 0; r < 4; ++r) {
        int c = lane + (r<<6);
        l[r]  = Lp[pb + c];
        mg[r] = Mp[pb + c];
        cf[r] = Cp[pb + c];
        sf[r] = Sp[pb + c];
    }
    const float l6 = Lp[pb + 256];
    const float m6 = Mp[pb + 256];
    const float c6 = Cp[pb + 256];

    float2* outbase = (float2*)out + (size_t)item * 16384;

    for (int t = 0; t < 4; ++t) {
        const int j = jg*16 + wv + (t<<2);
        const float gf = (j > 0) ? 1.0f : 0.0f;
        const float fj = (float)j;

        // ---- build S (regs) and V -> bufB: S = p*(m + (-1)^c*gf)*(cf,sf), V = p*(m - (-1)^c*gf)*(cf,sf)
        float2 S[4];
#pragma unroll
        for (int r = 0; r < 4; ++r) {
            int c = lane + (r<<6);
            float p = exp2f(fj * l[r]);
            float g = (c & 1) ? -gf : gf;
            float as = p * (mg[r] + g);
            float bs = p * (mg[r] - g);
            float2 Sv = make_float2(as * cf[r], as * sf[r]);
            float2 Vv = make_float2(bs * cf[r], bs * sf[r]);
            if (c == 0) { Sv.y = 0.0f; Vv.y = 0.0f; }   // numpy irfft drops imag of DC
            S[r] = Sv;
            bufB[c] = Vv;
        }
        float p6 = exp2f(fj * l6);
        float S6 = p6 * (m6 + gf) * c6;                  // bin 256 real (imag dropped)
        float V6 = p6 * (m6 - gf) * c6;
        if (lane == 0) bufB[256] = make_float2(V6, 0.0f);
        lgkm_sync();

        // ---- H[c] = 0.5*S[c] - 0.25*(V[c-1] + V[c+1]) -> bufA; edges use hermitian V[-1]=conj V[1]
#pragma unroll
        for (int r = 0; r < 4; ++r) {
            int c = lane + (r<<6);
            float2 Vm;
            if (c == 0) { float2 v1 = bufB[1]; Vm = make_float2(v1.x, -v1.y); }
            else Vm = bufB[c-1];
            float2 Vp = bufB[c+1];
            bufA[c] = make_float2(0.5f*S[r].x - 0.25f*(Vm.x + Vp.x),
                                  0.5f*S[r].y - 0.25f*(Vm.y + Vp.y));
        }
        if (lane == 0) {
            float2 v255 = bufB[255];
            bufA[256] = make_float2(0.5f*S6 - 0.5f*v255.x, 0.0f);
        }
        lgkm_sync();

        // ---- half-size packing: Z[k] = (1/512)[H[k](1+i w) + conj(H[256-k])(1-i w)] -> bufB[PH]
#pragma unroll
        for (int r = 0; r < 4; ++r) {
            int k = lane + (r<<6);
            float2 Hk = bufA[k];
            float2 Hm = bufA[256-k];
            float2 w = zwr[r];
            float Ar = Hk.x + Hm.x, Ai = Hk.y - Hm.y;
            float Br = Hk.x - Hm.x, Bi = Hk.y + Hm.y;
            float iwr = -w.y*Br - w.x*Bi;
            float iwi =  w.x*Br - w.y*Bi;
            bufB[PH(k)] = make_float2((Ar + iwr)*(1.0f/512.0f), (Ai + iwi)*(1.0f/512.0f));
        }
        lgkm_sync();

        // ---- 256-pt complex inverse FFT: radix-4 Stockham, stages 0..2 in LDS
        float2* src = bufB;
        float2* dst = bufA;
#pragma unroll
        for (int st = 0; st < 3; ++st) {
            const int sh = st << 1;          // 0,2,4
            const int s = 1 << sh;           // 1,4,16
            const int p = lane >> sh;
            const int q = lane & (s - 1);
            float2 A = src[PH(lane)];
            float2 B = src[PH(lane + 64)];
            float2 C = src[PH(lane + 128)];
            float2 D = src[PH(lane + 192)];
            float2 apc = cadd(A, C), amc = csub(A, C);
            float2 bpd = cadd(B, D);
            float2 jb = make_float2(D.y - B.y, B.x - D.x);   // +i*(B-D)
            int tb = p * s;                                   // twiddle base
            float2 w1 = tw[tb], w2 = tw[2*tb], w3 = tw[3*tb];
            int ob = q + 4*s*p;
            dst[PH(ob)]       = cadd(apc, bpd);
            dst[PH(ob + s)]   = cmul(w1, cadd(amc, jb));
            dst[PH(ob + 2*s)] = cmul(w2, csub(apc, bpd));
            dst[PH(ob + 3*s)] = cmul(w3, csub(amc, jb));
            lgkm_sync();
            float2* tmp = src; src = dst; dst = tmp;
        }

        // ---- stage 3 fused: twiddles = 1, outputs land in-lane; only lower half needed
        {
            float2 A = src[PH(lane)];
            float2 B = src[PH(lane + 64)];
            float2 C = src[PH(lane + 128)];
            float2 D = src[PH(lane + 192)];
            float2 apc = cadd(A, C), amc = csub(A, C);
            float2 bpd = cadd(B, D);
            float2 jb = make_float2(D.y - B.y, B.x - D.x);
            float2 y0 = cadd(apc, bpd);      // z[lane]
            float2 y1 = cadd(amc, jb);       // z[lane+64]
            float2* o2 = outbase + (j << 7);
            o2[lane] = y0;
            o2[lane + 64] = y1;
        }
        // next-t WAR hazards are covered by the per-phase lgkm_syncs (see derivation)
    }
}

extern "C" void kernel_launch(void* const* d_in, const int* in_sizes, int n_in,
                              void* d_out, int out_size, void* d_ws, size_t ws_size,
                              hipStream_t stream)
{
    const float* sel   = (const float*)d_in[0];   // (8,32,4,4096) f32 -> [1024][4096]
    const float* items = (const float*)d_in[1];   // (4096,514) f32
    float* out = (float*)d_out;                   // [1024][32768] f32 (33.55M floats)
    float* ws  = (float*)d_ws;

    // Scratch carved from d_out (dead by the time kres rewrites all of it):
    float* W     = out;                  // 1024*4096            = 4,194,304 floats
    float* Cpart = out + 4194304;        // KSPLIT*1024*NPAD     = 4,718,592 floats
    float* P     = ws;                   // 4*1024*257           = 1,052,672 floats (in ws)

    ksoftw<<<1024, 256, 0, stream>>>(sel, W);
    dim3 g2(16, 9, KSPLIT);
    kgemm2<<<g2, 256, 0, stream>>>(W, items, Cpart);
    ktrans<<<1024, 256, 0, stream>>>(Cpart, P);
    kres<<<8192, 256, 0, stream>>>(P, out);
}